// Round 1
// baseline (875.435 us; speedup 1.0000x reference)
//
#include <hip/hip_runtime.h>
#include <stdint.h>

// Triaffine: out[b,z,x,y] = sum_{i,j,k} xb[x,i] z[z,k] W[i,k,j] yb[y,j]
// B=4, S=128, D=512.  W: [513][512][513] f32 (i,k,j), elem (i,k,j) at (i*512+k)*513+j.
//
// Decomposition (bias split so all GEMM dims are 512):
//   M[bz,i,j] = sum_k z[bz,k] W[i,k,j]        (i,j < 512)   -- kernel G1, bf16 out
//   per bz:  R[i,y] = sum_j M[i,j] Ybf[y,j]                  -- kernel G2 pass-2
//            out[x,y] = sum_i Xbf[x,i] R[i,y] + u[x]+v[y]+d  -- kernel G2 pass-3
//   a[bz,i] = sum_k z W[i,k,512], c[bz,j] = sum_k z W[512,k,j], d = sum_k z W[512,k,512]
//   u[x] = x . a_bz, v[y] = y . c_bz  (computed in G2 epilogue-init)

typedef __attribute__((ext_vector_type(8))) short bf16x8;
typedef __attribute__((ext_vector_type(4))) float f32x4;

__device__ __forceinline__ unsigned short f2bf(float f) {
    unsigned int u = __float_as_uint(f);
    u += 0x7fffu + ((u >> 16) & 1u);      // RNE
    return (unsigned short)(u >> 16);
}

// ---------------- cast x,y,z -> bf16 ----------------
__global__ __launch_bounds__(256) void k_cast(const float* __restrict__ x,
    const float* __restrict__ y, const float* __restrict__ z,
    unsigned short* __restrict__ xbf, unsigned short* __restrict__ ybf,
    unsigned short* __restrict__ zbf)
{
    int t = blockIdx.x * 256 + threadIdx.x;   // 98304 threads, 8 elems each
    int arr = t >> 15;
    int off = (t & 32767) * 8;
    const float* src = (arr == 0) ? x : (arr == 1) ? y : z;
    unsigned short* dst = (arr == 0) ? xbf : (arr == 1) ? ybf : zbf;
    float4 a = *(const float4*)(src + off);
    float4 b = *(const float4*)(src + off + 4);
    uint4 o;
    o.x = f2bf(a.x) | ((unsigned)f2bf(a.y) << 16);
    o.y = f2bf(a.z) | ((unsigned)f2bf(a.w) << 16);
    o.z = f2bf(b.x) | ((unsigned)f2bf(b.y) << 16);
    o.w = f2bf(b.z) | ((unsigned)f2bf(b.w) << 16);
    *(uint4*)(dst + off) = o;
}

// ---------------- bias-edge GEMMs: a[bz,m<512], c[bz,m-512<512], d[bz,m==1024] ----------------
__global__ __launch_bounds__(256) void k_edge(const float* __restrict__ z,
    const float* __restrict__ w, float* __restrict__ a_arr,
    float* __restrict__ c_arr, float* __restrict__ d_arr)
{
    __shared__ float Zs[64][33];
    __shared__ float Bs[32][65];
    int t = threadIdx.x;
    int mb = blockIdx.x % 17, bzb = blockIdx.x / 17;
    int tr = t >> 4, tc = t & 15;
    float acc[4][4] = {};
    for (int k0 = 0; k0 < 512; k0 += 32) {
        __syncthreads();
        {   int row = t >> 2, ko = (t & 3) * 8;
            const float* p = z + (bzb * 64 + row) * 512 + k0 + ko;
            float4 v0 = ((const float4*)p)[0], v1 = ((const float4*)p)[1];
            Zs[row][ko + 0] = v0.x; Zs[row][ko + 1] = v0.y; Zs[row][ko + 2] = v0.z; Zs[row][ko + 3] = v0.w;
            Zs[row][ko + 4] = v1.x; Zs[row][ko + 5] = v1.y; Zs[row][ko + 6] = v1.z; Zs[row][ko + 7] = v1.w;
        }
        {   int kr = t >> 3, mo = (t & 7) * 8;
            for (int e = 0; e < 8; ++e) {
                int m = mb * 64 + mo + e;
                float v = 0.f;
                int krow = k0 + kr;
                if (m < 512)        v = w[(m * 512 + krow) * 513 + 512];
                else if (m < 1024)  v = w[(262144 + krow) * 513 + (m - 512)];
                else if (m == 1024) v = w[(262144 + krow) * 513 + 512];
                Bs[kr][mo + e] = v;
            }
        }
        __syncthreads();
        for (int kk = 0; kk < 32; ++kk) {
            float zr[4], br[4];
            for (int r = 0; r < 4; ++r) zr[r] = Zs[tr * 4 + r][kk];
            for (int c = 0; c < 4; ++c) br[c] = Bs[kk][tc * 4 + c];
            for (int r = 0; r < 4; ++r)
                for (int c = 0; c < 4; ++c) acc[r][c] += zr[r] * br[c];
        }
    }
    for (int r = 0; r < 4; ++r)
        for (int c = 0; c < 4; ++c) {
            int bz = bzb * 64 + tr * 4 + r;
            int m = mb * 64 + tc * 4 + c;
            if (m < 512)        a_arr[bz * 512 + m] = acc[r][c];
            else if (m < 1024)  c_arr[bz * 512 + (m - 512)] = acc[r][c];
            else if (m == 1024) d_arr[bz] = acc[r][c];
        }
}

// ---------------- G1: M[bz, i_local, j] = Z(bf16) x W(f32->bf16) ----------------
// tile: BM=512 (all bz, W streamed once), BN=64 (one i, j-block), BK=32.
// 8 waves = 4 bz-groups x 2 j-groups; wave tile 128bz x 32j; acc 8x2 frags.
__global__ __launch_bounds__(512) void k_gemm1(const unsigned short* __restrict__ zbf,
    const float* __restrict__ w, unsigned short* __restrict__ Mws,
    int i0, int chi)
{
    __shared__ unsigned short Alds[512 * 40];   // [row][k] stride 40 ush = 80 B (bank-spread, 16B-aligned)
    __shared__ unsigned short Blds[64 * 40];    // [j][k]   stride 40 ush
    int nwg = gridDim.x, cpx = nwg >> 3;
    int bid = blockIdx.x;
    int swz = (bid & 7) * cpx + (bid >> 3);     // XCD swizzle (nwg % 8 == 0)
    int iloc = swz >> 3, jb = swz & 7;
    int i = i0 + iloc;
    int j0 = jb * 64;
    int t = threadIdx.x;
    int wid = t >> 6, lane = t & 63;
    int bzg = wid >> 1, jg = wid & 1;
    int l15 = lane & 15, l4 = lane >> 4;
    f32x4 acc[8][2];
    for (int mt = 0; mt < 8; ++mt) for (int nt = 0; nt < 2; ++nt) acc[mt][nt] = (f32x4){0.f,0.f,0.f,0.f};

    int sj = t & 63, sk4 = (t >> 6) * 4;
    const float* wbase = w + (size_t)i * 262656 + j0 + sj;   // + k*513 per element

    for (int k0 = 0; k0 < 512; k0 += 32) {
        __syncthreads();
        {   // A stage: Zbf[row=t][k0..k0+32) -> Alds, 64 B
            const uint4* src = (const uint4*)(zbf + t * 512 + k0);
            uint4 v0 = src[0], v1 = src[1], v2 = src[2], v3 = src[3];
            uint4* dst = (uint4*)(Alds + t * 40);
            dst[0] = v0; dst[1] = v1; dst[2] = v2; dst[3] = v3;
        }
        {   // B stage: W[i, k0+sk4+0..4, j0+sj] -> Blds[j][k] (transposed, coalesced along j)
            float f0 = wbase[(size_t)(k0 + sk4 + 0) * 513];
            float f1 = wbase[(size_t)(k0 + sk4 + 1) * 513];
            float f2 = wbase[(size_t)(k0 + sk4 + 2) * 513];
            float f3 = wbase[(size_t)(k0 + sk4 + 3) * 513];
            unsigned p0 = f2bf(f0) | ((unsigned)f2bf(f1) << 16);
            unsigned p1 = f2bf(f2) | ((unsigned)f2bf(f3) << 16);
            *(uint2*)(Blds + sj * 40 + sk4) = make_uint2(p0, p1);
        }
        __syncthreads();
        bf16x8 bfr[2];
        for (int nt = 0; nt < 2; ++nt) {
            int jr = jg * 32 + nt * 16 + l15;
            bfr[nt] = *(const bf16x8*)(Blds + jr * 40 + l4 * 8);
        }
        for (int mt = 0; mt < 8; ++mt) {
            int row = bzg * 128 + mt * 16 + l15;
            bf16x8 afr = *(const bf16x8*)(Alds + row * 40 + l4 * 8);
            acc[mt][0] = __builtin_amdgcn_mfma_f32_16x16x32_bf16(afr, bfr[0], acc[mt][0], 0, 0, 0);
            acc[mt][1] = __builtin_amdgcn_mfma_f32_16x16x32_bf16(afr, bfr[1], acc[mt][1], 0, 0, 0);
        }
    }
    // store M[bz][iloc][j] bf16 (j-contiguous per 16 lanes -> 32B runs)
    for (int mt = 0; mt < 8; ++mt)
        for (int nt = 0; nt < 2; ++nt)
            for (int r = 0; r < 4; ++r) {
                int bz = bzg * 128 + mt * 16 + l4 * 4 + r;
                int j = j0 + jg * 32 + nt * 16 + l15;
                Mws[(size_t)bz * ((size_t)chi * 512) + (size_t)iloc * 512 + j] = f2bf(acc[mt][nt][r]);
            }
}

// ---------------- G2: per-bz fused  R = M x Y^T ;  out += X x R  (+bias terms) ----------------
// 8 waves. pass-2: (ig=wid>>2 x yg=wid&3), wave 32i x 32y. pass-3: (xg=wid>>2 x yg), wave 64x x 32y.
__global__ __launch_bounds__(512) void k_fuse(const unsigned short* __restrict__ xbf,
    const unsigned short* __restrict__ ybf, const unsigned short* __restrict__ Mws,
    const float* __restrict__ xf, const float* __restrict__ yf,
    const float* __restrict__ a_arr, const float* __restrict__ c_arr,
    const float* __restrict__ d_arr, float* __restrict__ out,
    int i0, int nib, int chi, int first)
{
    __shared__ unsigned short Xlds[128 * 72];   // [x][i]  stride 72 ush = 144 B
    __shared__ unsigned short Ylds[128 * 72];   // [y][j]
    __shared__ unsigned short Mlds[64 * 72];    // [i][j]
    __shared__ unsigned short Rlds[128 * 72];   // [y][i]
    int bid = blockIdx.x;
    int bz = (bid & 7) * 64 + (bid >> 3);       // XCD swizzle
    int b = bz >> 7;
    int t = threadIdx.x;
    int wid = t >> 6, lane = t & 63;
    int l15 = lane & 15, l4 = lane >> 4;
    int xg = wid >> 2, yg = wid & 3;

    f32x4 acc[4][2];
    if (first) {
        // u[x] = x . a_bz ; v[y] = y . c_bz  (scratch in Xlds, results in Ylds)
        float* part = (float*)Xlds;             // 512 f32
        float* uv = (float*)Ylds;               // u[128], v[128]
        int xr = t & 127, q = t >> 7;
        {   const float* xp = xf + (size_t)(b * 128 + xr) * 512 + q * 128;
            const float* ap = a_arr + bz * 512 + q * 128;
            float s = 0.f;
            for (int ii = 0; ii < 128; ++ii) s += xp[ii] * ap[ii];
            part[q * 128 + xr] = s;
        }
        __syncthreads();
        if (t < 128) uv[t] = part[t] + part[128 + t] + part[256 + t] + part[384 + t];
        __syncthreads();
        {   const float* yp = yf + (size_t)(b * 128 + xr) * 512 + q * 128;
            const float* cp = c_arr + bz * 512 + q * 128;
            float s = 0.f;
            for (int ii = 0; ii < 128; ++ii) s += yp[ii] * cp[ii];
            part[q * 128 + xr] = s;
        }
        __syncthreads();
        if (t < 128) uv[128 + t] = part[t] + part[128 + t] + part[256 + t] + part[384 + t];
        __syncthreads();
        float dv = d_arr[bz];
        for (int mt = 0; mt < 4; ++mt)
            for (int nt = 0; nt < 2; ++nt) {
                int y = yg * 32 + nt * 16 + l15;
                for (int r = 0; r < 4; ++r) {
                    int x = xg * 64 + mt * 16 + l4 * 4 + r;
                    acc[mt][nt][r] = uv[x] + uv[128 + y] + dv;
                }
            }
    } else {
        for (int mt = 0; mt < 4; ++mt) for (int nt = 0; nt < 2; ++nt) acc[mt][nt] = (f32x4){0.f,0.f,0.f,0.f};
    }

    for (int ibl = 0; ibl < nib; ++ibl) {
        __syncthreads();                         // prev pass-3 reads / uv scratch done
        {   // stage X[x][i-block]
            int xr = t >> 2, io = (t & 3) * 16;
            const uint4* src = (const uint4*)(xbf + (size_t)(b * 128 + xr) * 512 + i0 + ibl * 64 + io);
            uint4 v0 = src[0], v1 = src[1];
            uint4* dst = (uint4*)(Xlds + xr * 72 + io);
            dst[0] = v0; dst[1] = v1;
        }
        f32x4 accR[2][2];
        for (int mt = 0; mt < 2; ++mt) for (int nt = 0; nt < 2; ++nt) accR[mt][nt] = (f32x4){0.f,0.f,0.f,0.f};

        for (int jbk = 0; jbk < 8; ++jbk) {
            __syncthreads();                     // prev pass-2 reads done
            {   // stage Y[y][j-block]
                int yr = t >> 2, jo = (t & 3) * 16;
                const uint4* src = (const uint4*)(ybf + (size_t)(b * 128 + yr) * 512 + jbk * 64 + jo);
                uint4 v0 = src[0], v1 = src[1];
                uint4* dst = (uint4*)(Ylds + yr * 72 + jo);
                dst[0] = v0; dst[1] = v1;
            }
            {   // stage M[i-block][j-block]
                int ir = t >> 3, jo = (t & 7) * 8;
                uint4 v = *(const uint4*)(Mws + (size_t)bz * ((size_t)chi * 512)
                                              + (size_t)(ibl * 64 + ir) * 512 + jbk * 64 + jo);
                *(uint4*)(Mlds + ir * 72 + jo) = v;
            }
            __syncthreads();
            // pass-2: R[i,y] += sum_j M[i,j] * Y[y,j]
            for (int kf = 0; kf < 2; ++kf) {
                bf16x8 bfr[2];
                for (int nt = 0; nt < 2; ++nt) {
                    int y = yg * 32 + nt * 16 + l15;
                    bfr[nt] = *(const bf16x8*)(Ylds + y * 72 + kf * 32 + l4 * 8);
                }
                for (int mt = 0; mt < 2; ++mt) {
                    int ir = xg * 32 + mt * 16 + l15;
                    bf16x8 afr = *(const bf16x8*)(Mlds + ir * 72 + kf * 32 + l4 * 8);
                    accR[mt][0] = __builtin_amdgcn_mfma_f32_16x16x32_bf16(afr, bfr[0], accR[mt][0], 0, 0, 0);
                    accR[mt][1] = __builtin_amdgcn_mfma_f32_16x16x32_bf16(afr, bfr[1], accR[mt][1], 0, 0, 0);
                }
            }
        }
        // write R -> Rlds[y][i] bf16 (4 consecutive i per lane -> one 8B write)
        for (int mt = 0; mt < 2; ++mt)
            for (int nt = 0; nt < 2; ++nt) {
                int y = yg * 32 + nt * 16 + l15;
                int ir = xg * 32 + mt * 16 + l4 * 4;
                unsigned p0 = f2bf(accR[mt][nt][0]) | ((unsigned)f2bf(accR[mt][nt][1]) << 16);
                unsigned p1 = f2bf(accR[mt][nt][2]) | ((unsigned)f2bf(accR[mt][nt][3]) << 16);
                *(uint2*)(Rlds + y * 72 + ir) = make_uint2(p0, p1);
            }
        __syncthreads();
        // pass-3: out[x,y] += sum_i X[x,i] * R[i,y]
        for (int kf = 0; kf < 2; ++kf) {
            bf16x8 bfr[2];
            for (int nt = 0; nt < 2; ++nt) {
                int y = yg * 32 + nt * 16 + l15;
                bfr[nt] = *(const bf16x8*)(Rlds + y * 72 + kf * 32 + l4 * 8);
            }
            for (int mt = 0; mt < 4; ++mt) {
                int x = xg * 64 + mt * 16 + l15;
                bf16x8 afr = *(const bf16x8*)(Xlds + x * 72 + kf * 32 + l4 * 8);
                acc[mt][0] = __builtin_amdgcn_mfma_f32_16x16x32_bf16(afr, bfr[0], acc[mt][0], 0, 0, 0);
                acc[mt][1] = __builtin_amdgcn_mfma_f32_16x16x32_bf16(afr, bfr[1], acc[mt][1], 0, 0, 0);
            }
        }
    }
    // epilogue
    float* op = out + (size_t)bz * 16384;
    for (int mt = 0; mt < 4; ++mt)
        for (int nt = 0; nt < 2; ++nt)
            for (int r = 0; r < 4; ++r) {
                int x = xg * 64 + mt * 16 + l4 * 4 + r;
                int y = yg * 32 + nt * 16 + l15;
                if (first) op[x * 128 + y] = acc[mt][nt][r];
                else       op[x * 128 + y] += acc[mt][nt][r];
            }
}

extern "C" void kernel_launch(void* const* d_in, const int* in_sizes, int n_in,
                              void* d_out, int out_size, void* d_ws, size_t ws_size,
                              hipStream_t stream)
{
    const float* x = (const float*)d_in[0];
    const float* y = (const float*)d_in[1];
    const float* z = (const float*)d_in[2];
    const float* w = (const float*)d_in[3];
    float* out = (float*)d_out;
    char* ws = (char*)d_ws;

    unsigned short* xbf = (unsigned short*)(ws + 0);
    unsigned short* ybf = (unsigned short*)(ws + 524288);
    unsigned short* zbf = (unsigned short*)(ws + 1048576);
    float* a_arr = (float*)(ws + 1572864);
    float* c_arr = (float*)(ws + 2621440);
    float* d_arr = (float*)(ws + 3670016);
    unsigned short* Mws = (unsigned short*)(ws + 3674112);

    size_t avail = (ws_size > 3674112) ? ws_size - 3674112 : 0;
    int chi = 512;                                   // i-rows of M materialized per chunk
    while (chi > 64 && (size_t)chi * 524288 > avail) chi >>= 1;

    hipLaunchKernelGGL(k_cast, dim3(384), dim3(256), 0, stream, x, y, z, xbf, ybf, zbf);
    hipLaunchKernelGGL(k_edge, dim3(136), dim3(256), 0, stream, z, w, a_arr, c_arr, d_arr);

    int nch = 512 / chi;
    for (int c = 0; c < nch; ++c) {
        int i0 = c * chi;
        hipLaunchKernelGGL(k_gemm1, dim3(chi * 8), dim3(512), 0, stream, zbf, w, Mws, i0, chi);
        hipLaunchKernelGGL(k_fuse, dim3(512), dim3(512), 0, stream, xbf, ybf, Mws,
                           x, y, a_arr, c_arr, d_arr, out, i0, chi / 64, chi, (c == 0) ? 1 : 0);
    }
}

// Round 2
// 600.780 us; speedup vs baseline: 1.4572x; 1.4572x over previous
//
#include <hip/hip_runtime.h>
#include <stdint.h>

// Triaffine: out[b,z,x,y] = sum_{i,j,k} xb[x,i] z[z,k] W[i,k,j] yb[y,j]
// B=4, S=128, D=512.  W: [513][512][513] f32 (i,k,j), elem (i,k,j) at (i*512+k)*513+j.
//
// Decomposition (bias split so all GEMM dims are 512):
//   M[bz,i,j] = sum_k z[bz,k] W[i,k,j]        (i,j < 512)   -- kernel G1, bf16 out
//   per bz:  R[i,y] = sum_j M[i,j] Ybf[y,j]                  -- kernel G2 pass-2
//            out[x,y] = sum_i Xbf[x,i] R[i,y] + u[x]+v[y]+d  -- kernel G2 pass-3
//   a[bz,i] = sum_k z W[i,k,512], c[bz,j] = sum_k z W[512,k,j], d = sum_k z W[512,k,512]

typedef __attribute__((ext_vector_type(8))) short bf16x8;
typedef __attribute__((ext_vector_type(4))) float f32x4;

__device__ __forceinline__ unsigned short f2bf(float f) {
    unsigned int u = __float_as_uint(f);
    u += 0x7fffu + ((u >> 16) & 1u);      // RNE
    return (unsigned short)(u >> 16);
}

__device__ __forceinline__ void gload_lds16(const void* g, void* l) {
    __builtin_amdgcn_global_load_lds((const __attribute__((address_space(1))) void*)g,
                                     (__attribute__((address_space(3))) void*)l, 16, 0, 0);
}

// ---------------- cast x,y,z -> bf16 ----------------
__global__ __launch_bounds__(256) void k_cast(const float* __restrict__ x,
    const float* __restrict__ y, const float* __restrict__ z,
    unsigned short* __restrict__ xbf, unsigned short* __restrict__ ybf,
    unsigned short* __restrict__ zbf)
{
    int t = blockIdx.x * 256 + threadIdx.x;   // 98304 threads, 8 elems each
    int arr = t >> 15;
    int off = (t & 32767) * 8;
    const float* src = (arr == 0) ? x : (arr == 1) ? y : z;
    unsigned short* dst = (arr == 0) ? xbf : (arr == 1) ? ybf : zbf;
    float4 a = *(const float4*)(src + off);
    float4 b = *(const float4*)(src + off + 4);
    uint4 o;
    o.x = f2bf(a.x) | ((unsigned)f2bf(a.y) << 16);
    o.y = f2bf(a.z) | ((unsigned)f2bf(a.w) << 16);
    o.z = f2bf(b.x) | ((unsigned)f2bf(b.y) << 16);
    o.w = f2bf(b.z) | ((unsigned)f2bf(b.w) << 16);
    *(uint4*)(dst + off) = o;
}

// ---------------- bias-edge GEMMs ----------------
__global__ __launch_bounds__(256) void k_edge(const float* __restrict__ z,
    const float* __restrict__ w, float* __restrict__ a_arr,
    float* __restrict__ c_arr, float* __restrict__ d_arr)
{
    __shared__ float Zs[64][33];
    __shared__ float Bs[32][65];
    int t = threadIdx.x;
    int mb = blockIdx.x % 17, bzb = blockIdx.x / 17;
    int tr = t >> 4, tc = t & 15;
    float acc[4][4] = {};
    for (int k0 = 0; k0 < 512; k0 += 32) {
        __syncthreads();
        {   int row = t >> 2, ko = (t & 3) * 8;
            const float* p = z + (bzb * 64 + row) * 512 + k0 + ko;
            float4 v0 = ((const float4*)p)[0], v1 = ((const float4*)p)[1];
            Zs[row][ko + 0] = v0.x; Zs[row][ko + 1] = v0.y; Zs[row][ko + 2] = v0.z; Zs[row][ko + 3] = v0.w;
            Zs[row][ko + 4] = v1.x; Zs[row][ko + 5] = v1.y; Zs[row][ko + 6] = v1.z; Zs[row][ko + 7] = v1.w;
        }
        {   int kr = t >> 3, mo = (t & 7) * 8;
            for (int e = 0; e < 8; ++e) {
                int m = mb * 64 + mo + e;
                float v = 0.f;
                int krow = k0 + kr;
                if (m < 512)        v = w[(m * 512 + krow) * 513 + 512];
                else if (m < 1024)  v = w[(262144 + krow) * 513 + (m - 512)];
                else if (m == 1024) v = w[(262144 + krow) * 513 + 512];
                Bs[kr][mo + e] = v;
            }
        }
        __syncthreads();
        for (int kk = 0; kk < 32; ++kk) {
            float zr[4], br[4];
            for (int r = 0; r < 4; ++r) zr[r] = Zs[tr * 4 + r][kk];
            for (int c = 0; c < 4; ++c) br[c] = Bs[kk][tc * 4 + c];
            for (int r = 0; r < 4; ++r)
                for (int c = 0; c < 4; ++c) acc[r][c] += zr[r] * br[c];
        }
    }
    for (int r = 0; r < 4; ++r)
        for (int c = 0; c < 4; ++c) {
            int bz = bzb * 64 + tr * 4 + r;
            int m = mb * 64 + tc * 4 + c;
            if (m < 512)        a_arr[bz * 512 + m] = acc[r][c];
            else if (m < 1024)  c_arr[bz * 512 + (m - 512)] = acc[r][c];
            else if (m == 1024) d_arr[bz] = acc[r][c];
        }
}

// ---------------- G1: M[bz, i_local, j] = Z(bf16) x W(f32->bf16) ----------------
// BM=512 (all bz; W streamed exactly once), BN=64, BK=32, 16 K-steps.
// 8 waves = 4 bz-grp x 2 j-grp; wave tile 128bz x 32j; acc[8][2].
// Double-buffered LDS, ONE barrier per K-step:
//   A (Z rows) via global_load_lds w=16, linear dest + pre-swizzled source;
//   B (W tile) reg-staged: loads issued before MFMA block, pack+ds_write after.
// LDS XOR swizzle: byte = row*64 + (kbyte ^ ((row&8)<<2)) on both A and B.
__global__ __launch_bounds__(512, 4) void k_gemm1(const unsigned short* __restrict__ zbf,
    const float* __restrict__ w, unsigned short* __restrict__ Mws,
    int i0, int chi)
{
    extern __shared__ unsigned char smem[];
    unsigned char* Ab0 = smem;                 // [512 rows][32 k] bf16 = 32 KB
    unsigned char* Ab1 = smem + 32768;
    unsigned char* Bb0 = smem + 65536;         // [64 j][32 k] bf16 = 4 KB
    unsigned char* Bb1 = smem + 69632;         // total 73728 B

    int nwg = gridDim.x;
    int cpx = nwg >> 3;
    int bid = blockIdx.x;
    int swz = (bid & 7) * cpx + (bid >> 3);    // XCD swizzle (nwg % 8 == 0)
    int iloc = swz >> 3, jb = swz & 7;
    int j0 = jb * 64;
    int t = threadIdx.x, wid = t >> 6, lane = t & 63;
    int bzg = wid >> 1, jg = wid & 1;
    int l15 = lane & 15, l4 = lane >> 4;

    // A-stage source mapping (pre-swizzled so linear LDS dest == swizzled layout)
    int arow = lane >> 2;                      // 0..15 row within 16-row block
    int akc  = (lane & 3) ^ ((lane >> 4) & 2); // 16B k-chunk, XOR for rows 8..15
    const unsigned short* zbase = zbf + (size_t)(wid * 64 + arow) * 512 + akc * 8;

    // B-stage: thread t -> j = t&63, k-quad kq = t>>6 (4 scalar W loads, 1 b64 LDS write)
    int jB = t & 63, kq = t >> 6;
    const float* wb = w + (size_t)(i0 + iloc) * 262656 + (size_t)(kq * 4) * 513 + j0 + jB;
    int bwoff = jB * 64 + ((kq * 8) ^ ((jB & 8) << 2));

    // fragment read offsets (swizzled); mt/nt stride = 16 rows * 64 B = 1024
    int aoff0 = (bzg * 128 + l15) * 64 + ((l4 * 16) ^ ((l15 & 8) << 2));
    int boff0 = (jg * 32 + l15) * 64 + ((l4 * 16) ^ ((l15 & 8) << 2));

    f32x4 acc[8][2];
    #pragma unroll
    for (int mt = 0; mt < 8; ++mt)
        #pragma unroll
        for (int nt = 0; nt < 2; ++nt) acc[mt][nt] = (f32x4){0.f, 0.f, 0.f, 0.f};

    // ---- prologue: stage K-step 0 into buf 0 ----
    #pragma unroll
    for (int q = 0; q < 4; ++q)
        gload_lds16(zbase + q * 8192, Ab0 + wid * 4096 + q * 1024);
    {
        float b0 = wb[0], b1 = wb[513], b2 = wb[1026], b3 = wb[1539];
        unsigned p0 = f2bf(b0) | ((unsigned)f2bf(b1) << 16);
        unsigned p1 = f2bf(b2) | ((unsigned)f2bf(b3) << 16);
        *(uint2*)(Bb0 + bwoff) = make_uint2(p0, p1);
    }

    unsigned char* Acur = Ab0; unsigned char* Anext = Ab1;
    unsigned char* Bcur = Bb0; unsigned char* Bnext = Bb1;

    for (int ks = 0; ks < 16; ++ks) {
        __syncthreads();                       // buf[cur] staged & visible; buf[next] free
        float b0, b1, b2, b3;
        if (ks < 15) {
            int k0n = (ks + 1) * 32;
            #pragma unroll
            for (int q = 0; q < 4; ++q)
                gload_lds16(zbase + k0n + q * 8192, Anext + wid * 4096 + q * 1024);
            const float* wp = wb + (size_t)k0n * 513;
            b0 = wp[0]; b1 = wp[513]; b2 = wp[1026]; b3 = wp[1539];
        }
        // compute on current buffers (loads above stay in flight under the MFMAs)
        bf16x8 bfr0 = *(const bf16x8*)(Bcur + boff0);
        bf16x8 bfr1 = *(const bf16x8*)(Bcur + boff0 + 1024);
        #pragma unroll
        for (int mt = 0; mt < 8; ++mt) {
            bf16x8 afr = *(const bf16x8*)(Acur + aoff0 + mt * 1024);
            acc[mt][0] = __builtin_amdgcn_mfma_f32_16x16x32_bf16(afr, bfr0, acc[mt][0], 0, 0, 0);
            acc[mt][1] = __builtin_amdgcn_mfma_f32_16x16x32_bf16(afr, bfr1, acc[mt][1], 0, 0, 0);
        }
        if (ks < 15) {
            // pack + transposed write (implicit vmcnt wait drains A gloads too)
            unsigned p0 = f2bf(b0) | ((unsigned)f2bf(b1) << 16);
            unsigned p1 = f2bf(b2) | ((unsigned)f2bf(b3) << 16);
            *(uint2*)(Bnext + bwoff) = make_uint2(p0, p1);
        }
        unsigned char* tmp = Acur; Acur = Anext; Anext = tmp;
        tmp = Bcur; Bcur = Bnext; Bnext = tmp;
    }

    // ---- epilogue: store M[bz][iloc][j] bf16 ----
    size_t mrow = (size_t)chi * 512;
    #pragma unroll
    for (int mt = 0; mt < 8; ++mt)
        #pragma unroll
        for (int nt = 0; nt < 2; ++nt)
            #pragma unroll
            for (int r = 0; r < 4; ++r) {
                int bz = bzg * 128 + mt * 16 + l4 * 4 + r;
                int j  = j0 + jg * 32 + nt * 16 + l15;
                Mws[(size_t)bz * mrow + (size_t)iloc * 512 + j] = f2bf(acc[mt][nt][r]);
            }
}

// ---------------- G2: per-bz fused  R = M x Y^T ;  out += X x R  (+bias terms) ----------------
__global__ __launch_bounds__(512) void k_fuse(const unsigned short* __restrict__ xbf,
    const unsigned short* __restrict__ ybf, const unsigned short* __restrict__ Mws,
    const float* __restrict__ xf, const float* __restrict__ yf,
    const float* __restrict__ a_arr, const float* __restrict__ c_arr,
    const float* __restrict__ d_arr, float* __restrict__ out,
    int i0, int nib, int chi, int first)
{
    __shared__ unsigned short Xlds[128 * 72];   // [x][i]  stride 72 ush = 144 B
    __shared__ unsigned short Ylds[128 * 72];   // [y][j]
    __shared__ unsigned short Mlds[64 * 72];    // [i][j]
    __shared__ unsigned short Rlds[128 * 72];   // [y][i]
    int bid = blockIdx.x;
    int bz = (bid & 7) * 64 + (bid >> 3);       // XCD swizzle
    int b = bz >> 7;
    int t = threadIdx.x;
    int wid = t >> 6, lane = t & 63;
    int l15 = lane & 15, l4 = lane >> 4;
    int xg = wid >> 2, yg = wid & 3;

    f32x4 acc[4][2];
    if (first) {
        float* part = (float*)Xlds;             // 512 f32
        float* uv = (float*)Ylds;               // u[128], v[128]
        int xr = t & 127, q = t >> 7;
        {   const float* xp = xf + (size_t)(b * 128 + xr) * 512 + q * 128;
            const float* ap = a_arr + bz * 512 + q * 128;
            float s = 0.f;
            for (int ii = 0; ii < 128; ++ii) s += xp[ii] * ap[ii];
            part[q * 128 + xr] = s;
        }
        __syncthreads();
        if (t < 128) uv[t] = part[t] + part[128 + t] + part[256 + t] + part[384 + t];
        __syncthreads();
        {   const float* yp = yf + (size_t)(b * 128 + xr) * 512 + q * 128;
            const float* cp = c_arr + bz * 512 + q * 128;
            float s = 0.f;
            for (int ii = 0; ii < 128; ++ii) s += yp[ii] * cp[ii];
            part[q * 128 + xr] = s;
        }
        __syncthreads();
        if (t < 128) uv[128 + t] = part[t] + part[128 + t] + part[256 + t] + part[384 + t];
        __syncthreads();
        float dv = d_arr[bz];
        for (int mt = 0; mt < 4; ++mt)
            for (int nt = 0; nt < 2; ++nt) {
                int y = yg * 32 + nt * 16 + l15;
                for (int r = 0; r < 4; ++r) {
                    int x = xg * 64 + mt * 16 + l4 * 4 + r;
                    acc[mt][nt][r] = uv[x] + uv[128 + y] + dv;
                }
            }
    } else {
        for (int mt = 0; mt < 4; ++mt) for (int nt = 0; nt < 2; ++nt) acc[mt][nt] = (f32x4){0.f,0.f,0.f,0.f};
    }

    for (int ibl = 0; ibl < nib; ++ibl) {
        __syncthreads();
        {   int xr = t >> 2, io = (t & 3) * 16;
            const uint4* src = (const uint4*)(xbf + (size_t)(b * 128 + xr) * 512 + i0 + ibl * 64 + io);
            uint4 v0 = src[0], v1 = src[1];
            uint4* dst = (uint4*)(Xlds + xr * 72 + io);
            dst[0] = v0; dst[1] = v1;
        }
        f32x4 accR[2][2];
        for (int mt = 0; mt < 2; ++mt) for (int nt = 0; nt < 2; ++nt) accR[mt][nt] = (f32x4){0.f,0.f,0.f,0.f};

        for (int jbk = 0; jbk < 8; ++jbk) {
            __syncthreads();
            {   int yr = t >> 2, jo = (t & 3) * 16;
                const uint4* src = (const uint4*)(ybf + (size_t)(b * 128 + yr) * 512 + jbk * 64 + jo);
                uint4 v0 = src[0], v1 = src[1];
                uint4* dst = (uint4*)(Ylds + yr * 72 + jo);
                dst[0] = v0; dst[1] = v1;
            }
            {   int ir = t >> 3, jo = (t & 7) * 8;
                uint4 v = *(const uint4*)(Mws + (size_t)bz * ((size_t)chi * 512)
                                              + (size_t)(ibl * 64 + ir) * 512 + jbk * 64 + jo);
                *(uint4*)(Mlds + ir * 72 + jo) = v;
            }
            __syncthreads();
            for (int kf = 0; kf < 2; ++kf) {
                bf16x8 bfr[2];
                for (int nt = 0; nt < 2; ++nt) {
                    int y = yg * 32 + nt * 16 + l15;
                    bfr[nt] = *(const bf16x8*)(Ylds + y * 72 + kf * 32 + l4 * 8);
                }
                for (int mt = 0; mt < 2; ++mt) {
                    int ir = xg * 32 + mt * 16 + l15;
                    bf16x8 afr = *(const bf16x8*)(Mlds + ir * 72 + kf * 32 + l4 * 8);
                    accR[mt][0] = __builtin_amdgcn_mfma_f32_16x16x32_bf16(afr, bfr[0], accR[mt][0], 0, 0, 0);
                    accR[mt][1] = __builtin_amdgcn_mfma_f32_16x16x32_bf16(afr, bfr[1], accR[mt][1], 0, 0, 0);
                }
            }
        }
        for (int mt = 0; mt < 2; ++mt)
            for (int nt = 0; nt < 2; ++nt) {
                int y = yg * 32 + nt * 16 + l15;
                int ir = xg * 32 + mt * 16 + l4 * 4;
                unsigned p0 = f2bf(accR[mt][nt][0]) | ((unsigned)f2bf(accR[mt][nt][1]) << 16);
                unsigned p1 = f2bf(accR[mt][nt][2]) | ((unsigned)f2bf(accR[mt][nt][3]) << 16);
                *(uint2*)(Rlds + y * 72 + ir) = make_uint2(p0, p1);
            }
        __syncthreads();
        for (int kf = 0; kf < 2; ++kf) {
            bf16x8 bfr[2];
            for (int nt = 0; nt < 2; ++nt) {
                int y = yg * 32 + nt * 16 + l15;
                bfr[nt] = *(const bf16x8*)(Rlds + y * 72 + kf * 32 + l4 * 8);
            }
            for (int mt = 0; mt < 4; ++mt) {
                int x = xg * 64 + mt * 16 + l15;
                bf16x8 afr = *(const bf16x8*)(Xlds + x * 72 + kf * 32 + l4 * 8);
                acc[mt][0] = __builtin_amdgcn_mfma_f32_16x16x32_bf16(afr, bfr[0], acc[mt][0], 0, 0, 0);
                acc[mt][1] = __builtin_amdgcn_mfma_f32_16x16x32_bf16(afr, bfr[1], acc[mt][1], 0, 0, 0);
            }
        }
    }
    float* op = out + (size_t)bz * 16384;
    for (int mt = 0; mt < 4; ++mt)
        for (int nt = 0; nt < 2; ++nt)
            for (int r = 0; r < 4; ++r) {
                int x = xg * 64 + mt * 16 + l4 * 4 + r;
                int y = yg * 32 + nt * 16 + l15;
                if (first) op[x * 128 + y] = acc[mt][nt][r];
                else       op[x * 128 + y] += acc[mt][nt][r];
            }
}

extern "C" void kernel_launch(void* const* d_in, const int* in_sizes, int n_in,
                              void* d_out, int out_size, void* d_ws, size_t ws_size,
                              hipStream_t stream)
{
    const float* x = (const float*)d_in[0];
    const float* y = (const float*)d_in[1];
    const float* z = (const float*)d_in[2];
    const float* w = (const float*)d_in[3];
    float* out = (float*)d_out;
    char* ws = (char*)d_ws;

    unsigned short* xbf = (unsigned short*)(ws + 0);
    unsigned short* ybf = (unsigned short*)(ws + 524288);
    unsigned short* zbf = (unsigned short*)(ws + 1048576);
    float* a_arr = (float*)(ws + 1572864);
    float* c_arr = (float*)(ws + 2621440);
    float* d_arr = (float*)(ws + 3670016);
    unsigned short* Mws = (unsigned short*)(ws + 3674112);

    size_t avail = (ws_size > 3674112) ? ws_size - 3674112 : 0;
    int chi = 512;                                   // i-rows of M materialized per chunk
    while (chi > 64 && (size_t)chi * 524288 > avail) chi >>= 1;

    hipLaunchKernelGGL(k_cast, dim3(384), dim3(256), 0, stream, x, y, z, xbf, ybf, zbf);
    hipLaunchKernelGGL(k_edge, dim3(136), dim3(256), 0, stream, z, w, a_arr, c_arr, d_arr);

    int nch = 512 / chi;
    for (int c = 0; c < nch; ++c) {
        int i0 = c * chi;
        hipLaunchKernelGGL(k_gemm1, dim3(chi * 8), dim3(512), 73728, stream, zbf, w, Mws, i0, chi);
        hipLaunchKernelGGL(k_fuse, dim3(512), dim3(512), 0, stream, xbf, ybf, Mws,
                           x, y, a_arr, c_arr, d_arr, out, i0, chi / 64, chi, (c == 0) ? 1 : 0);
    }
}